// Round 13
// baseline (64.299 us; speedup 1.0000x reference)
//
#include <hip/hip_runtime.h>
#include <math.h>

#define NTOK 16384
#define DK   2048
#define NEXP 64

typedef float f32x4 __attribute__((ext_vector_type(4)));
typedef int   i32x4 __attribute__((ext_vector_type(4)));
typedef short s16x8 __attribute__((ext_vector_type(8)));

// ---- scalar RTNE fp32->bf16 ----
__device__ __forceinline__ unsigned short f2bf(float f) {
    union { float f; unsigned u; } v; v.f = f;
    unsigned r = (v.u + 0x7FFFu + ((v.u >> 16) & 1u)) >> 16;
    return (unsigned short)r;
}
__device__ __forceinline__ float bf2f(unsigned short h) {
    union { unsigned u; float f; } v; v.u = ((unsigned)h) << 16;
    return v.f;
}

// Pre-kernel: 3-way bf16 split of W, packed in MFMA B-fragment order:
// ws[R][n][p][lane][8 shorts], R = global K32-round 0..63, lane = g*16+rr
// holds expert 16n+rr, k = R*32 + g*8..+8, plane p. 1 KB contiguous per frag.
__global__ __launch_bounds__(256) void wsplit_pack(const float* __restrict__ Wg,
                                                   unsigned short* __restrict__ ws) {
    const int t  = blockIdx.x * 256 + threadIdx.x;  // 16384 = 64 experts x 256 k-octets
    const int e  = t >> 8;
    const int k  = (t & 255) * 8;
    const int R  = k >> 5;          // global round
    const int g  = (k >> 3) & 3;
    const int rr = e & 15;
    const int n  = e >> 4;
    const int lane = g * 16 + rr;

    const float* src = Wg + (size_t)e * DK + k;
    unsigned short p0[8], p1[8], p2[8];
    #pragma unroll
    for (int j = 0; j < 8; ++j) {
        const float f = src[j];
        p0[j] = f2bf(f);  const float r1 = f - bf2f(p0[j]);
        p1[j] = f2bf(r1); const float r2 = r1 - bf2f(p1[j]);
        p2[j] = f2bf(r2);
    }
    const size_t base = (((size_t)R * 4 + n) * 3) * 512 + (size_t)lane * 8;
    *(s16x8*)(ws + base)        = *(s16x8*)p0;
    *(s16x8*)(ws + base + 512)  = *(s16x8*)p1;
    *(s16x8*)(ws + base + 1024) = *(s16x8*)p2;
}

// Async global->LDS, 16B/lane (dst wave-uniform; HW adds lane*16).
__device__ __forceinline__ void gload_lds16(const float* src, float* dst) {
    __builtin_amdgcn_global_load_lds(
        (const __attribute__((address_space(1))) void*)src,
        (__attribute__((address_space(3))) void*)dst, 16, 0, 0);
}

__device__ __forceinline__ unsigned cvtpk(float lo, float hi) {
    unsigned r;
    asm("v_cvt_pk_bf16_f32 %0, %1, %2" : "=v"(r) : "v"(lo), "v"(hi));
    return r;
}

#define SPLIT2(F0, F1, O0, O1, O2) { \
    const unsigned q0 = cvtpk((F0), (F1)); \
    const float s0 = (F0) - __builtin_bit_cast(float, q0 << 16); \
    const float s1 = (F1) - __builtin_bit_cast(float, q0 & 0xFFFF0000u); \
    const unsigned q1 = cvtpk(s0, s1); \
    const float t0 = s0 - __builtin_bit_cast(float, q1 << 16); \
    const float t1 = s1 - __builtin_bit_cast(float, q1 & 0xFFFF0000u); \
    O0 = (int)q0; O1 = (int)q1; O2 = (int)cvtpk(t0, t1); }

#define ISSUE_X(XS, c) { \
    _Pragma("unroll") for (int m = 0; m < 2; ++m) \
        _Pragma("unroll") for (int h = 0; h < 2; ++h) \
            XS[m][h] = *(const float4*)(xbase + (size_t)m * 16 * DK + h * 4 + (c) * 32); }

// Block-cooperative B staging: wave w stages frags w*3..w*3+2 (3 gload_lds).
#define STAGE_B(c, BUF) { \
    _Pragma("unroll") for (int j = 0; j < 3; ++j) { \
        const int f = w3 + j; \
        gload_lds16(wsf + ((size_t)(R0 + (c)) * 12 + f) * 256 + lane4, \
                    &bB[BUF][f * 256]); } }

#define CONV1(XS, m) { \
    SPLIT2(XS[m][0].x, XS[m][0].y, A[m][0].x, A[m][1].x, A[m][2].x); \
    SPLIT2(XS[m][0].z, XS[m][0].w, A[m][0].y, A[m][1].y, A[m][2].y); \
    SPLIT2(XS[m][1].x, XS[m][1].y, A[m][0].z, A[m][1].z, A[m][2].z); \
    SPLIT2(XS[m][1].z, XS[m][1].w, A[m][0].w, A[m][1].w, A[m][2].w); }

#define MFMA1(Aa, Bb, Cc) __builtin_amdgcn_mfma_f32_16x16x32_bf16( \
    __builtin_bit_cast(s16x8, Aa), __builtin_bit_cast(s16x8, Bb), Cc, 0, 0, 0)

// Per n-group: 3 LDS frag reads, 12 MFMA (6 split-terms x 2 m).
#define MFMA_N(n, BUF) { \
    const i32x4 bn0 = *(const i32x4*)&bB[BUF][((n) * 3 + 0) * 256 + lane4]; \
    const i32x4 bn1 = *(const i32x4*)&bB[BUF][((n) * 3 + 1) * 256 + lane4]; \
    const i32x4 bn2 = *(const i32x4*)&bB[BUF][((n) * 3 + 2) * 256 + lane4]; \
    _Pragma("unroll") for (int m = 0; m < 2; ++m) { \
        acc[m][n] = MFMA1(A[m][0], bn0, acc[m][n]); \
        acc[m][n] = MFMA1(A[m][0], bn1, acc[m][n]); \
        acc[m][n] = MFMA1(A[m][1], bn0, acc[m][n]); \
        acc[m][n] = MFMA1(A[m][1], bn1, acc[m][n]); \
        acc[m][n] = MFMA1(A[m][0], bn2, acc[m][n]); \
        acc[m][n] = MFMA1(A[m][2], bn0, acc[m][n]); } }

// One round: counted vmcnt + RAW s_barrier (no __syncthreads -> no vmcnt(0)
// drain). 3-buffer rotation makes stage(c+2) write-safe vs readers of BUF.
#define ROUND(c, XS, BUF, NCNT, DO_ISSUE, NBUF) { \
    asm volatile("s_waitcnt vmcnt(" #NCNT ")" ::: "memory"); \
    __builtin_amdgcn_sched_barrier(0); \
    __builtin_amdgcn_s_barrier(); \
    __builtin_amdgcn_sched_barrier(0); \
    CONV1(XS, 0); CONV1(XS, 1); \
    MFMA_N(0, BUF) MFMA_N(1, BUF) MFMA_N(2, BUF) MFMA_N(3, BUF) \
    if (DO_ISSUE) { STAGE_B((c) + 2, NBUF); ISSUE_X(XS, (c) + 2); } \
    __builtin_amdgcn_sched_barrier(0); }

// GEMM: block = 4 waves x 32 tokens (same K-slice), grid = 128 tok-grp x 8 K.
// Partials to d_ws; reduce kernel does the K-combine + top-2.
__global__ __launch_bounds__(256, 3) void topk_gemm(
    const float* __restrict__ x,            // [NTOK][DK]
    const unsigned short* __restrict__ ws,  // packed B frags (768 KB)
    float* __restrict__ part)               // [8][NTOK][64] fp32 partial logits
{
    __shared__ float bB[3][3072];           // 3-deep rotation x 12 KB B-round

    const int tid  = threadIdx.x;
    const int w    = tid >> 6;
    const int lane = tid & 63;
    const int rr   = lane & 15;
    const int g    = lane >> 4;
    const int w3   = w * 3;
    const int lane4 = lane * 4;
    const int tg   = blockIdx.x >> 3;       // token group (128 tokens)
    const int ks   = blockIdx.x & 7;        // K-slice (256 k = 8 rounds)
    const int R0   = ks * 8;                // global round base
    const int tok0 = tg * 128 + w * 32;
    const float* wsf = (const float*)ws;

    const float* xbase = x + (size_t)(tok0 + rr) * DK + ks * 256 + g * 8;

    f32x4 acc[2][4];
    #pragma unroll
    for (int m = 0; m < 2; ++m)
        #pragma unroll
        for (int n = 0; n < 4; ++n) acc[m][n] = (f32x4){0.f, 0.f, 0.f, 0.f};

    float4 X0[2][2], X1[2][2];
    i32x4  A[2][3];

    // prologue: rounds 0,1 in flight (7 VMEM each: 3 B-stage + 4 x)
    STAGE_B(0, 0); ISSUE_X(X0, 0);
    STAGE_B(1, 1); ISSUE_X(X1, 1);

    // 8 rounds, bufs c%3, issue c+2 while c+2<8; vmcnt(7) = older round landed
    ROUND(0, X0, 0, 7, 1, 2);
    ROUND(1, X1, 1, 7, 1, 0);
    ROUND(2, X0, 2, 7, 1, 1);
    ROUND(3, X1, 0, 7, 1, 2);
    ROUND(4, X0, 1, 7, 1, 0);
    ROUND(5, X1, 2, 7, 1, 1);
    ROUND(6, X0, 0, 7, 0, 0);
    ROUND(7, X1, 1, 0, 0, 0);

    // partial-logit store (D layout: col=lane&15, row=(lane>>4)*4+reg)
    float* pbase = part + ((size_t)ks << 20);   // ks * 16384 * 64
    #pragma unroll
    for (int m = 0; m < 2; ++m)
        #pragma unroll
        for (int n = 0; n < 4; ++n)
            #pragma unroll
            for (int r = 0; r < 4; ++r)
                pbase[(size_t)(tok0 + m * 16 + g * 4 + r) * 64 + n * 16 + rr]
                    = acc[m][n][r];
}

// Reduce: sum 8 K-slices, top-2, output. One wave per 16 tokens, lane=expert.
__global__ __launch_bounds__(256) void topk_reduce(
    const float* __restrict__ part,   // [8][NTOK][64]
    float* __restrict__ out)
{
    const int tid  = threadIdx.x;
    const int wv   = tid >> 6;
    const int lane = tid & 63;
    const int tokb = blockIdx.x * 64 + wv * 16;

    #pragma unroll 1
    for (int t = 0; t < 16; ++t) {
        const int tok = tokb + t;
        float v = 0.f;
        #pragma unroll
        for (int s = 0; s < 8; ++s)
            v += part[((size_t)s << 20) + (size_t)tok * 64 + lane];

        // top-1 (tie -> lower index, matching lax.top_k)
        float m1 = v; int i1 = lane;
        #pragma unroll
        for (int off = 32; off > 0; off >>= 1) {
            float ov = __shfl_xor(m1, off);
            int   oi = __shfl_xor(i1, off);
            if (ov > m1 || (ov == m1 && oi < i1)) { m1 = ov; i1 = oi; }
        }
        // top-2: mask out winner
        float m2 = (lane == i1) ? -INFINITY : v; int i2 = lane;
        #pragma unroll
        for (int off = 32; off > 0; off >>= 1) {
            float ov = __shfl_xor(m2, off);
            int   oi = __shfl_xor(i2, off);
            if (ov > m2 || (ov == m2 && oi < i2)) { m2 = ov; i2 = oi; }
        }

        if (lane == 0) {
            const float e  = expf(m2 - m1);
            const float w1 = 1.0f / (1.0f + e);
            const float w2 = e / (1.0f + e);
            out[tok * 2 + 0] = (float)i1;
            out[tok * 2 + 1] = (float)i2;
            out[NTOK * 2 + tok * 2 + 0] = w1;
            out[NTOK * 2 + tok * 2 + 1] = w2;
        }
    }
}

extern "C" void kernel_launch(void* const* d_in, const int* in_sizes, int n_in,
                              void* d_out, int out_size, void* d_ws, size_t ws_size,
                              hipStream_t stream) {
    const float* x  = (const float*)d_in[0];
    const float* Wg = (const float*)d_in[1];
    float* out = (float*)d_out;
    unsigned short* ws = (unsigned short*)d_ws;           // 768 KB packed B
    float* part = (float*)((char*)d_ws + (1 << 20));      // 32 MB partials

    hipLaunchKernelGGL(wsplit_pack, dim3(64), dim3(256), 0, stream, Wg, ws);
    // 1024 blocks x 256 thr, 3 waves/SIMD: B shared via LDS (98 MB total vs
    // 393 private), counted vmcnt + raw s_barrier (no per-round vmcnt(0) drain)
    hipLaunchKernelGGL(topk_gemm, dim3(1024), dim3(256), 0, stream, x, ws, part);
    hipLaunchKernelGGL(topk_reduce, dim3(256), dim3(256), 0, stream, part, out);
}

// Round 14
// 47.872 us; speedup vs baseline: 1.3431x; 1.3431x over previous
//
#include <hip/hip_runtime.h>
#include <math.h>

#define NTOK 16384
#define DK   2048
#define NEXP 64

typedef float f32x4 __attribute__((ext_vector_type(4)));
typedef int   i32x4 __attribute__((ext_vector_type(4)));
typedef short s16x8 __attribute__((ext_vector_type(8)));

// ---- scalar RTNE fp32->bf16 ----
__device__ __forceinline__ unsigned short f2bf(float f) {
    union { float f; unsigned u; } v; v.f = f;
    unsigned r = (v.u + 0x7FFFu + ((v.u >> 16) & 1u)) >> 16;
    return (unsigned short)r;
}
__device__ __forceinline__ float bf2f(unsigned short h) {
    union { unsigned u; float f; } v; v.u = ((unsigned)h) << 16;
    return v.f;
}

// Pre-kernel: 3-way bf16 split of W, PACKED in MFMA B-fragment order (r11):
// ws[w][c][n][p][lane][8 shorts], lane = g*16 + rr holds expert 16n+rr,
// k = w*512 + c*32 + g*8..+8, plane p. 1 KB contiguous per (c,n,p) frag.
__global__ __launch_bounds__(256) void wsplit_pack(const float* __restrict__ Wg,
                                                   unsigned short* __restrict__ ws) {
    const int t  = blockIdx.x * 256 + threadIdx.x;  // 16384 = 64 experts x 256 k-octets
    const int e  = t >> 8;
    const int k  = (t & 255) * 8;
    const int w  = k >> 9;
    const int c  = (k >> 5) & 15;
    const int g  = (k >> 3) & 3;
    const int rr = e & 15;
    const int n  = e >> 4;
    const int lane = g * 16 + rr;

    const float* src = Wg + (size_t)e * DK + k;
    unsigned short p0[8], p1[8], p2[8];
    #pragma unroll
    for (int j = 0; j < 8; ++j) {
        const float f = src[j];
        p0[j] = f2bf(f);  const float r1 = f - bf2f(p0[j]);
        p1[j] = f2bf(r1); const float r2 = r1 - bf2f(p1[j]);
        p2[j] = f2bf(r2);
    }
    const size_t base = ((((size_t)w * 16 + c) * 4 + n) * 3) * 512 + (size_t)lane * 8;
    *(s16x8*)(ws + base)        = *(s16x8*)p0;
    *(s16x8*)(ws + base + 512)  = *(s16x8*)p1;
    *(s16x8*)(ws + base + 1024) = *(s16x8*)p2;
}

// Async global->LDS, 16B/lane (dst wave-uniform; HW adds lane*16).
__device__ __forceinline__ void gload_lds16(const float* src, float* dst) {
    __builtin_amdgcn_global_load_lds(
        (const __attribute__((address_space(1))) void*)src,
        (__attribute__((address_space(3))) void*)dst, 16, 0, 0);
}

__device__ __forceinline__ unsigned cvtpk(float lo, float hi) {
    unsigned r;
    asm("v_cvt_pk_bf16_f32 %0, %1, %2" : "=v"(r) : "v"(lo), "v"(hi));
    return r;
}

#define SPLIT2(F0, F1, O0, O1, O2) { \
    const unsigned q0 = cvtpk((F0), (F1)); \
    const float s0 = (F0) - __builtin_bit_cast(float, q0 << 16); \
    const float s1 = (F1) - __builtin_bit_cast(float, q0 & 0xFFFF0000u); \
    const unsigned q1 = cvtpk(s0, s1); \
    const float t0 = s0 - __builtin_bit_cast(float, q1 << 16); \
    const float t1 = s1 - __builtin_bit_cast(float, q1 & 0xFFFF0000u); \
    O0 = (int)q0; O1 = (int)q1; O2 = (int)cvtpk(t0, t1); }

// x staging: COALESCED. Each gload_lds16 = 8 token-rows x 128 B dense
// segments (full line use). 4 instrs cover the [32 tok][32 k] round-chunk.
// (r9-r13 loaded x frag-direct = 16-row x 64B-granule scatter -> the 45 us
// plateau was the x stream at ~3 TB/s effective.)
#define STAGE_X(c, BUF) { \
    _Pragma("unroll") for (int it = 0; it < 4; ++it) \
        gload_lds16(xsrc + (size_t)it * 8 * DK + (size_t)(c) * 32, \
                    &xs[w][BUF][it * 256]); }

// Per round: 4 x-stage + 12 B = 16 VMEM (the vmcnt unit).
#define ISSUE_B(BS, c) { \
    _Pragma("unroll") for (int n = 0; n < 4; ++n) \
        _Pragma("unroll") for (int p = 0; p < 3; ++p) \
            BS[n][p] = *(const i32x4*)(wbase + ((size_t)(c) * 12 + n * 3 + p) * 512); }

// A-frags from LDS: linear [32 rows][32 floats]; per (m,h) read the 64 lanes
// hit 64 distinct granules = 32 banks x 8 words = pure data-min delivery.
#define CONV_LDS(BUF) { \
    _Pragma("unroll") for (int m = 0; m < 2; ++m) { \
        const float4 xa0 = *(const float4*)&xs[w][BUF][(rr + 16 * m) * 32 + g * 8]; \
        const float4 xa1 = *(const float4*)&xs[w][BUF][(rr + 16 * m) * 32 + g * 8 + 4]; \
        SPLIT2(xa0.x, xa0.y, A[m][0].x, A[m][1].x, A[m][2].x); \
        SPLIT2(xa0.z, xa0.w, A[m][0].y, A[m][1].y, A[m][2].y); \
        SPLIT2(xa1.x, xa1.y, A[m][0].z, A[m][1].z, A[m][2].z); \
        SPLIT2(xa1.z, xa1.w, A[m][0].w, A[m][1].w, A[m][2].w); } }

#define MFMA_TERM(pa, pb, BS) { \
    _Pragma("unroll") for (int m = 0; m < 2; ++m) \
        _Pragma("unroll") for (int n = 0; n < 4; ++n) \
            acc[m][n] = __builtin_amdgcn_mfma_f32_16x16x32_bf16( \
                __builtin_bit_cast(s16x8, A[m][pa]), \
                __builtin_bit_cast(s16x8, BS[n][pb]), acc[m][n], 0, 0, 0); }

// 6 terms: (0,0),(0,1),(1,0),(1,1),(0,2),(2,0) -> logit exact to ~2^-24 rel
#define MFMA_ALL(BS) \
    MFMA_TERM(0, 0, BS) MFMA_TERM(0, 1, BS) MFMA_TERM(1, 0, BS) \
    MFMA_TERM(1, 1, BS) MFMA_TERM(0, 2, BS) MFMA_TERM(2, 0, BS)

// Steady phase: 32 VMEM outstanding (rounds c, c+1); vmcnt(16) retires round c
// (x-stage LDS writes included). No barriers: buffers are wave-private.
#define PHASE(BS, c, NCNT, DO_ISSUE) { \
    asm volatile("s_waitcnt vmcnt(" #NCNT ")" ::: "memory"); \
    __builtin_amdgcn_sched_barrier(0); \
    CONV_LDS((c) & 1); \
    MFMA_ALL(BS); \
    if (DO_ISSUE) { STAGE_X((c) + 2, (c) & 1); ISSUE_B(BS, (c) + 2); } \
    __builtin_amdgcn_sched_barrier(0); }

__global__ __launch_bounds__(256, 2) void topk_router_kernel(
    const float* __restrict__ x,            // [NTOK][DK] fp32
    const unsigned short* __restrict__ ws,  // packed B frags (768 KB)
    float* __restrict__ out)                // [NTOK*2] idx (as float) ++ [NTOK*2] w
{
    // xs: wave-private x staging [4 waves][2 bufs][32 tok x 32 k] = 32 KB.
    // lg overlays the same smem after the epilogue barrier (8704 floats).
    __shared__ float smem[8704];
    float (*xs)[2][1024] = (float (*)[2][1024])smem;
    float (*lg)[32][68]  = (float (*)[32][68])smem;

    const int tid  = threadIdx.x;
    const int w    = tid >> 6;              // wave 0..3 == K-quarter
    const int lane = tid & 63;
    const int rr   = lane & 15;
    const int g    = lane >> 4;
    const int tok0 = blockIdx.x * 32;

    // staging lane decomposition: lane = lt*8 + lq -> row lt, 16B-granule lq
    const int lt = lane >> 3;
    const int lq = lane & 7;
    const float* xsrc = x + (size_t)(tok0 + lt) * DK + w * 512 + lq * 4;
    // B: packed frags for this wave's K-quarter; 1 KB contiguous per frag.
    const unsigned short* wbase = ws + (size_t)w * 98304 + (size_t)lane * 8;

    f32x4 acc[2][4];
    #pragma unroll
    for (int m = 0; m < 2; ++m)
        #pragma unroll
        for (int n = 0; n < 4; ++n) acc[m][n] = (f32x4){0.f, 0.f, 0.f, 0.f};

    i32x4 B0[4][3], B1[4][3];
    i32x4 A[2][3];

    // ---- prologue: rounds 0,1 in flight (16 VMEM each) ----
    STAGE_X(0, 0); ISSUE_B(B0, 0);
    STAGE_X(1, 1); ISSUE_B(B1, 1);

    // ---- main: rounds 0..13 (issue c+2), tail 14,15 ----
    #pragma unroll 1
    for (int c = 0; c < 14; c += 2) {
        PHASE(B0, c,     16, 1);
        PHASE(B1, c + 1, 16, 1);
    }
    PHASE(B0, 14, 16, 0);
    PHASE(B1, 15,  0, 0);

    // ---- combine 4 K-quarters (the only barriers) ----
    __syncthreads();   // also: all staging retired (vmcnt(0) in last PHASE)
    #pragma unroll
    for (int m = 0; m < 2; ++m)
        #pragma unroll
        for (int n = 0; n < 4; ++n)
            #pragma unroll
            for (int r = 0; r < 4; ++r)
                lg[w][m * 16 + g * 4 + r][n * 16 + rr] = acc[m][n][r];
    __syncthreads();

    // ---- top-2 per token: wave w -> tokens w*8..+7, lane = expert ----
    #pragma unroll 1
    for (int t = 0; t < 8; ++t) {
        const int tok = w * 8 + t;
        const float v = lg[0][tok][lane] + lg[1][tok][lane]
                      + lg[2][tok][lane] + lg[3][tok][lane];

        // top-1 (tie -> lower index, matching lax.top_k)
        float m1 = v; int i1 = lane;
        #pragma unroll
        for (int off = 32; off > 0; off >>= 1) {
            float ov = __shfl_xor(m1, off);
            int   oi = __shfl_xor(i1, off);
            if (ov > m1 || (ov == m1 && oi < i1)) { m1 = ov; i1 = oi; }
        }
        // top-2: mask out winner
        float m2 = (lane == i1) ? -INFINITY : v; int i2 = lane;
        #pragma unroll
        for (int off = 32; off > 0; off >>= 1) {
            float ov = __shfl_xor(m2, off);
            int   oi = __shfl_xor(i2, off);
            if (ov > m2 || (ov == m2 && oi < i2)) { m2 = ov; i2 = oi; }
        }

        if (lane == 0) {
            const int gtok = tok0 + tok;
            // softmax denom cancels: w1 = 1/(1+e^{l2-l1}), w2 = 1 - w1
            const float e  = expf(m2 - m1);
            const float w1 = 1.0f / (1.0f + e);
            const float w2 = e / (1.0f + e);
            out[gtok * 2 + 0] = (float)i1;
            out[gtok * 2 + 1] = (float)i2;
            out[NTOK * 2 + gtok * 2 + 0] = w1;
            out[NTOK * 2 + gtok * 2 + 1] = w2;
        }
    }
}

extern "C" void kernel_launch(void* const* d_in, const int* in_sizes, int n_in,
                              void* d_out, int out_size, void* d_ws, size_t ws_size,
                              hipStream_t stream) {
    const float* x  = (const float*)d_in[0];
    const float* Wg = (const float*)d_in[1];
    float* out = (float*)d_out;
    unsigned short* ws = (unsigned short*)d_ws;   // 768 KB packed B
    hipLaunchKernelGGL(wsplit_pack, dim3(64), dim3(256), 0, stream, Wg, ws);
    // 512 blocks x 256 thr = 2048 waves (2/SIMD): coalesced x via LDS,
    // packed B in registers, 2-deep counted-vmcnt pipeline, no in-loop barriers.
    hipLaunchKernelGGL(topk_router_kernel, dim3(NTOK / 32), dim3(256), 0, stream,
                       x, ws, out);
}

// Round 15
// 47.718 us; speedup vs baseline: 1.3475x; 1.0032x over previous
//
#include <hip/hip_runtime.h>
#include <math.h>

#define NTOK 16384
#define DK   2048
#define NEXP 64

typedef float f32x4 __attribute__((ext_vector_type(4)));
typedef int   i32x4 __attribute__((ext_vector_type(4)));
typedef short s16x8 __attribute__((ext_vector_type(8)));

// ---- scalar RTNE fp32->bf16 ----
__device__ __forceinline__ unsigned short f2bf(float f) {
    union { float f; unsigned u; } v; v.f = f;
    unsigned r = (v.u + 0x7FFFu + ((v.u >> 16) & 1u)) >> 16;
    return (unsigned short)r;
}
__device__ __forceinline__ float bf2f(unsigned short h) {
    union { unsigned u; float f; } v; v.u = ((unsigned)h) << 16;
    return v.f;
}

// Pre-kernel: 3-way bf16 split of W, PACKED in MFMA B-fragment order (r11):
// ws[w][c][n][p][lane][8 shorts], lane = g*16 + rr holds expert 16n+rr,
// k = w*512 + c*32 + g*8..+8, plane p. 1 KB contiguous per (c,n,p) frag.
__global__ __launch_bounds__(256) void wsplit_pack(const float* __restrict__ Wg,
                                                   unsigned short* __restrict__ ws) {
    const int t  = blockIdx.x * 256 + threadIdx.x;  // 16384 = 64 experts x 256 k-octets
    const int e  = t >> 8;
    const int k  = (t & 255) * 8;
    const int w  = k >> 9;
    const int c  = (k >> 5) & 15;
    const int g  = (k >> 3) & 3;
    const int rr = e & 15;
    const int n  = e >> 4;
    const int lane = g * 16 + rr;

    const float* src = Wg + (size_t)e * DK + k;
    unsigned short p0[8], p1[8], p2[8];
    #pragma unroll
    for (int j = 0; j < 8; ++j) {
        const float f = src[j];
        p0[j] = f2bf(f);  const float r1 = f - bf2f(p0[j]);
        p1[j] = f2bf(r1); const float r2 = r1 - bf2f(p1[j]);
        p2[j] = f2bf(r2);
    }
    const size_t base = ((((size_t)w * 16 + c) * 4 + n) * 3) * 512 + (size_t)lane * 8;
    *(s16x8*)(ws + base)        = *(s16x8*)p0;
    *(s16x8*)(ws + base + 512)  = *(s16x8*)p1;
    *(s16x8*)(ws + base + 1024) = *(s16x8*)p2;
}

// Async global->LDS, 16B/lane (dst wave-uniform; HW adds lane*16).
__device__ __forceinline__ void gload_lds16(const float* src, float* dst) {
    __builtin_amdgcn_global_load_lds(
        (const __attribute__((address_space(1))) void*)src,
        (__attribute__((address_space(3))) void*)dst, 16, 0, 0);
}

__device__ __forceinline__ unsigned cvtpk(float lo, float hi) {
    unsigned r;
    asm("v_cvt_pk_bf16_f32 %0, %1, %2" : "=v"(r) : "v"(lo), "v"(hi));
    return r;
}

#define SPLIT2(F0, F1, O0, O1, O2) { \
    const unsigned q0 = cvtpk((F0), (F1)); \
    const float s0 = (F0) - __builtin_bit_cast(float, q0 << 16); \
    const float s1 = (F1) - __builtin_bit_cast(float, q0 & 0xFFFF0000u); \
    const unsigned q1 = cvtpk(s0, s1); \
    const float t0 = s0 - __builtin_bit_cast(float, q1 << 16); \
    const float t1 = s1 - __builtin_bit_cast(float, q1 & 0xFFFF0000u); \
    O0 = (int)q0; O1 = (int)q1; O2 = (int)cvtpk(t0, t1); }

// x staging, coalesced AND bank-swizzled (rule #21 both-sides XOR):
// LDS slot s of row r holds global 16B-granule (s ^ (r&7)). Stage fetches
// granule (lq ^ lt) so the linear gload_lds dest realizes that layout; the
// read XORs again -> identity on data. r14's linear tile had row*32 = 0 mod
// 32 banks -> ds_read_b128's 16 same-g lanes hit ONE bank quad = 16-way
// conflict; the swizzle makes it 2 rows/slot = 2-way = free (m136).
#define STAGE_X(c, BUF) { \
    _Pragma("unroll") for (int it = 0; it < 4; ++it) \
        gload_lds16(xsrc + (size_t)it * 8 * DK + (size_t)(c) * 32, \
                    &xs[w][BUF][it * 256]); }

// Per round: 4 x-stage + 12 B = 16 VMEM (the vmcnt unit).
#define ISSUE_B(BS, c) { \
    _Pragma("unroll") for (int n = 0; n < 4; ++n) \
        _Pragma("unroll") for (int p = 0; p < 3; ++p) \
            BS[n][p] = *(const i32x4*)(wbase + ((size_t)(c) * 12 + n * 3 + p) * 512); }

// A-frags from LDS with the inverse swizzle on the granule slot.
#define CONV_LDS(BUF) { \
    _Pragma("unroll") for (int m = 0; m < 2; ++m) { \
        const int row = rr + 16 * m; \
        const int sw  = row & 7; \
        const float4 xa0 = *(const float4*)&xs[w][BUF][row * 32 + (((g * 2 + 0) ^ sw) << 2)]; \
        const float4 xa1 = *(const float4*)&xs[w][BUF][row * 32 + (((g * 2 + 1) ^ sw) << 2)]; \
        SPLIT2(xa0.x, xa0.y, A[m][0].x, A[m][1].x, A[m][2].x); \
        SPLIT2(xa0.z, xa0.w, A[m][0].y, A[m][1].y, A[m][2].y); \
        SPLIT2(xa1.x, xa1.y, A[m][0].z, A[m][1].z, A[m][2].z); \
        SPLIT2(xa1.z, xa1.w, A[m][0].w, A[m][1].w, A[m][2].w); } }

#define MFMA_TERM(pa, pb, BS) { \
    _Pragma("unroll") for (int m = 0; m < 2; ++m) \
        _Pragma("unroll") for (int n = 0; n < 4; ++n) \
            acc[m][n] = __builtin_amdgcn_mfma_f32_16x16x32_bf16( \
                __builtin_bit_cast(s16x8, A[m][pa]), \
                __builtin_bit_cast(s16x8, BS[n][pb]), acc[m][n], 0, 0, 0); }

// 6 terms: (0,0),(0,1),(1,0),(1,1),(0,2),(2,0) -> logit exact to ~2^-24 rel
#define MFMA_ALL(BS) \
    MFMA_TERM(0, 0, BS) MFMA_TERM(0, 1, BS) MFMA_TERM(1, 0, BS) \
    MFMA_TERM(1, 1, BS) MFMA_TERM(0, 2, BS) MFMA_TERM(2, 0, BS)

// Steady phase: 32 VMEM outstanding (rounds c, c+1); vmcnt(16) retires round c
// (x-stage LDS writes included). No barriers: buffers are wave-private.
#define PHASE(BS, c, NCNT, DO_ISSUE) { \
    asm volatile("s_waitcnt vmcnt(" #NCNT ")" ::: "memory"); \
    __builtin_amdgcn_sched_barrier(0); \
    CONV_LDS((c) & 1); \
    MFMA_ALL(BS); \
    if (DO_ISSUE) { STAGE_X((c) + 2, (c) & 1); ISSUE_B(BS, (c) + 2); } \
    __builtin_amdgcn_sched_barrier(0); }

__global__ __launch_bounds__(256, 2) void topk_router_kernel(
    const float* __restrict__ x,            // [NTOK][DK] fp32
    const unsigned short* __restrict__ ws,  // packed B frags (768 KB)
    float* __restrict__ out)                // [NTOK*2] idx (as float) ++ [NTOK*2] w
{
    // xs: wave-private x staging [4 waves][2 bufs][32 tok x 32 k] = 32 KB.
    // lg overlays the same smem after the epilogue barrier (8704 floats).
    __shared__ float smem[8704];
    float (*xs)[2][1024] = (float (*)[2][1024])smem;
    float (*lg)[32][68]  = (float (*)[32][68])smem;

    const int tid  = threadIdx.x;
    const int w    = tid >> 6;              // wave 0..3 == K-quarter
    const int lane = tid & 63;
    const int rr   = lane & 15;
    const int g    = lane >> 4;
    const int tok0 = blockIdx.x * 32;

    // staging lane decomposition: lane = lt*8 + lq -> row lt (+8*it), slot lq.
    // Pre-swizzled SOURCE granule = lq ^ lt (involution with the read XOR);
    // per-row 128 B coverage is a permutation -> coalescing unchanged.
    const int lt = lane >> 3;
    const int lq = lane & 7;
    const float* xsrc = x + (size_t)(tok0 + lt) * DK + w * 512 + ((lq ^ lt) * 4);
    // B: packed frags for this wave's K-quarter; 1 KB contiguous per frag.
    const unsigned short* wbase = ws + (size_t)w * 98304 + (size_t)lane * 8;

    f32x4 acc[2][4];
    #pragma unroll
    for (int m = 0; m < 2; ++m)
        #pragma unroll
        for (int n = 0; n < 4; ++n) acc[m][n] = (f32x4){0.f, 0.f, 0.f, 0.f};

    i32x4 B0[4][3], B1[4][3];
    i32x4 A[2][3];

    // ---- prologue: rounds 0,1 in flight (16 VMEM each) ----
    STAGE_X(0, 0); ISSUE_B(B0, 0);
    STAGE_X(1, 1); ISSUE_B(B1, 1);

    // ---- main: rounds 0..13 (issue c+2), tail 14,15 ----
    #pragma unroll 1
    for (int c = 0; c < 14; c += 2) {
        PHASE(B0, c,     16, 1);
        PHASE(B1, c + 1, 16, 1);
    }
    PHASE(B0, 14, 16, 0);
    PHASE(B1, 15,  0, 0);

    // ---- combine 4 K-quarters (the only barriers) ----
    __syncthreads();   // also: all staging retired (vmcnt(0) in last PHASE)
    #pragma unroll
    for (int m = 0; m < 2; ++m)
        #pragma unroll
        for (int n = 0; n < 4; ++n)
            #pragma unroll
            for (int r = 0; r < 4; ++r)
                lg[w][m * 16 + g * 4 + r][n * 16 + rr] = acc[m][n][r];
    __syncthreads();

    // ---- top-2 per token: wave w -> tokens w*8..+7, lane = expert ----
    #pragma unroll 1
    for (int t = 0; t < 8; ++t) {
        const int tok = w * 8 + t;
        const float v = lg[0][tok][lane] + lg[1][tok][lane]
                      + lg[2][tok][lane] + lg[3][tok][lane];

        // top-1 (tie -> lower index, matching lax.top_k)
        float m1 = v; int i1 = lane;
        #pragma unroll
        for (int off = 32; off > 0; off >>= 1) {
            float ov = __shfl_xor(m1, off);
            int   oi = __shfl_xor(i1, off);
            if (ov > m1 || (ov == m1 && oi < i1)) { m1 = ov; i1 = oi; }
        }
        // top-2: mask out winner
        float m2 = (lane == i1) ? -INFINITY : v; int i2 = lane;
        #pragma unroll
        for (int off = 32; off > 0; off >>= 1) {
            float ov = __shfl_xor(m2, off);
            int   oi = __shfl_xor(i2, off);
            if (ov > m2 || (ov == m2 && oi < i2)) { m2 = ov; i2 = oi; }
        }

        if (lane == 0) {
            const int gtok = tok0 + tok;
            // softmax denom cancels: w1 = 1/(1+e^{l2-l1}), w2 = 1 - w1
            const float e  = expf(m2 - m1);
            const float w1 = 1.0f / (1.0f + e);
            const float w2 = e / (1.0f + e);
            out[gtok * 2 + 0] = (float)i1;
            out[gtok * 2 + 1] = (float)i2;
            out[NTOK * 2 + gtok * 2 + 0] = w1;
            out[NTOK * 2 + gtok * 2 + 1] = w2;
        }
    }
}

extern "C" void kernel_launch(void* const* d_in, const int* in_sizes, int n_in,
                              void* d_out, int out_size, void* d_ws, size_t ws_size,
                              hipStream_t stream) {
    const float* x  = (const float*)d_in[0];
    const float* Wg = (const float*)d_in[1];
    float* out = (float*)d_out;
    unsigned short* ws = (unsigned short*)d_ws;   // 768 KB packed B
    hipLaunchKernelGGL(wsplit_pack, dim3(64), dim3(256), 0, stream, Wg, ws);
    // 512 blocks x 256 thr = 2048 waves (2/SIMD): coalesced+swizzled x via LDS,
    // packed B in registers, 2-deep counted-vmcnt pipeline, no in-loop barriers.
    hipLaunchKernelGGL(topk_router_kernel, dim3(NTOK / 32), dim3(256), 0, stream,
                       x, ws, out);
}